// Round 3
// baseline (23459.633 us; speedup 1.0000x reference)
//
#include <hip/hip_runtime.h>
#include <cstdint>
#include <cstddef>

// GRU: T=512, B=64, I=256, H=1024, O=256, L=3
#define TT 512
#define BB 64
#define II 256
#define HH 1024
#define OO 256
#define LL 3
#define NBLK 192

typedef _Float16 half8 __attribute__((ext_vector_type(8)));
typedef float floatx4 __attribute__((ext_vector_type(4)));
typedef float float4v __attribute__((ext_vector_type(4)));

__device__ __forceinline__ floatx4 mfma16(half8 a, half8 b, floatx4 c) {
    return __builtin_amdgcn_mfma_f32_16x16x32_f16(a, b, c, 0, 0, 0);
}

__global__ void cast_f32_f16(const float* __restrict__ in, _Float16* __restrict__ out, int n) {
    int i = blockIdx.x * 256 + threadIdx.x;
    if (i < n) out[i] = (_Float16)in[i];
}

__global__ void init_h(const float* __restrict__ h0, float* __restrict__ h32,
                       _Float16* __restrict__ h16, unsigned* __restrict__ bar) {
    int i = blockIdx.x * 256 + threadIdx.x;
    if (i == 0) *bar = 0u;
    if (i >= LL * BB * HH) return;
    int l = i / (BB * HH);
    int rest = i - l * (BB * HH);
    float v = h0[i];
    size_t b0 = ((size_t)l * 2 + 0) * BB * HH + rest;
    size_t b1 = ((size_t)l * 2 + 1) * BB * HH + rest;
    h32[b0] = v; h32[b1] = v;
    h16[b0] = (_Float16)v; h16[b1] = (_Float16)v;
}

// Reorder weight [3H][K] (f32) into MFMA B-fragment order (f16).
// chunk idx = ((jb*3 + g)*nks + ks)*64 + lane; chunk = 8 halfs =
// W[g*H + jb*16 + (lane&15)][kcol0 + ks*32 + (lane>>4)*8 .. +8)
__global__ void frag_reorder(const float* __restrict__ src, _Float16* __restrict__ dst,
                             int K, int nks, int kcol0) {
    int idx = blockIdx.x * 256 + threadIdx.x;
    int total = 64 * 3 * nks * 64;
    if (idx >= total) return;
    int lane = idx & 63;
    int r = idx >> 6;
    int ks = r % nks; r /= nks;
    int g = r % 3;
    int jb = r / 3;
    int row = g * HH + jb * 16 + (lane & 15);
    int col = kcol0 + ks * 32 + (lane >> 4) * 8;
    const float* s8 = src + (size_t)row * K + col;
    half8 v;
#pragma unroll
    for (int i = 0; i < 8; ++i) v[i] = (_Float16)s8[i];
    *(half8*)(dst + (size_t)idx * 8) = v;
}

struct PArgs {
    const _Float16* x16;
    const _Float16* whh_lo[3];   // frag order, nks=16, K in [0,512)
    const _Float16* whh_hi[3];   // frag order, nks=16, K in [512,1024)
    const _Float16* wih[3];      // frag order; [0]: nks=8 (K=256), [1,2]: nks=32
    const float* bih[3];
    const float* bhh[3];
    float* h32;        // [L][2][B][H] fp32 master (parity dbuf, block-local)
    _Float16* h16;     // [L][2][B][H] fp16 shadow (cross-block)
    _Float16* y2;      // [T][B][H] layer-2 outputs for FC
    float* out_h;      // d_out + T*B*O
    unsigned* bar;     // epoch barrier counter
};

// Persistent pipelined GRU. 192 blocks x 256 threads (plain launch).
// block = (layer = bid>>6, jb = bid&63 -> cols jb*16..+16).
// LDS: K-lo half of w_hh slice (48KB). wave wv owns rows wv*16..+16.
__global__ __launch_bounds__(256, 1) void gru_persistent(PArgs a) {
    __shared__ char lds[49152];
    const int layer = blockIdx.x >> 6;
    const int jb = blockIdx.x & 63;
    const int tid = threadIdx.x;
    const int lane = tid & 63;
    const int wv = tid >> 6;
    const int lr = lane & 15, lq = lane >> 4;
    const int row0 = wv << 4;
    const int j = (jb << 4) + lr;

    const _Float16* whh_hi = a.whh_hi[layer] + (size_t)jb * 24576 + (size_t)lane * 8;
    const int wih_nks = (layer == 0) ? 8 : 32;
    const _Float16* wih = a.wih[layer] + (size_t)jb * (size_t)(3 * wih_nks * 64 * 8)
                          + (size_t)lane * 8;
    const float* bih = a.bih[layer];
    const float* bhh = a.bhh[layer];

    // one-time LDS preload (fragment-ordered contiguous copy, 48KB)
    {
        const float4v* src = (const float4v*)(a.whh_lo[layer] + (size_t)jb * 24576);
        float4v* dst = (float4v*)lds;
        for (int i = tid; i < 3072; i += 256) dst[i] = src[i];
    }
    __syncthreads();

    const float bir = bih[j], biz = bih[HH + j], bin = bih[2 * HH + j];
    const float bhr = bhh[j], bhz = bhh[HH + j], bhn = bhh[2 * HH + j];
    const char* wb = lds + (size_t)lane * 16;

    for (int s = 0; s < TT + LL - 1; ++s) {
        const int t = s - layer;
        if (t >= 0 && t < TT) {
            const int pr = (s + 1) & 1, pw = s & 1;
            floatx4 ar{0.f,0.f,0.f,0.f}, az{0.f,0.f,0.f,0.f};
            floatx4 ani{0.f,0.f,0.f,0.f}, anh{0.f,0.f,0.f,0.f};
            const _Float16* Ah = a.h16 + ((size_t)(layer * 2 + pr)) * BB * HH
                                 + (size_t)(row0 + lr) * HH + lq * 8;

            if (layer == 0) {
                const _Float16* Ax = a.x16 + (size_t)t * BB * II
                                     + (size_t)(row0 + lr) * II + lq * 8;
#pragma unroll
                for (int ks = 0; ks < 8; ++ks) {       // x-side, streamed w_ih0
                    half8 av = *(const half8*)(Ax + ks * 32);
                    ar  = mfma16(av, *(const half8*)(wih + (size_t)(0 * 8 + ks) * 512), ar);
                    az  = mfma16(av, *(const half8*)(wih + (size_t)(1 * 8 + ks) * 512), az);
                    ani = mfma16(av, *(const half8*)(wih + (size_t)(2 * 8 + ks) * 512), ani);
                }
#pragma unroll
                for (int ks = 0; ks < 16; ++ks) {      // h-side K-lo from LDS
                    half8 av = *(const half8*)(Ah + ks * 32);
                    ar  = mfma16(av, *(const half8*)(wb + (0 * 16 + ks) * 1024), ar);
                    az  = mfma16(av, *(const half8*)(wb + (1 * 16 + ks) * 1024), az);
                    anh = mfma16(av, *(const half8*)(wb + (2 * 16 + ks) * 1024), anh);
                }
#pragma unroll
                for (int ks = 0; ks < 16; ++ks) {      // h-side K-hi streamed
                    half8 av = *(const half8*)(Ah + 512 + ks * 32);
                    ar  = mfma16(av, *(const half8*)(whh_hi + (size_t)(0 * 16 + ks) * 512), ar);
                    az  = mfma16(av, *(const half8*)(whh_hi + (size_t)(1 * 16 + ks) * 512), az);
                    anh = mfma16(av, *(const half8*)(whh_hi + (size_t)(2 * 16 + ks) * 512), anh);
                }
            } else {
                const _Float16* Ay = a.h16 + ((size_t)((layer - 1) * 2 + pr)) * BB * HH
                                     + (size_t)(row0 + lr) * HH + lq * 8;
#pragma unroll
                for (int ks = 0; ks < 16; ++ks) {      // K-lo: LDS w_hh + streamed w_ih
                    half8 avh = *(const half8*)(Ah + ks * 32);
                    half8 avy = *(const half8*)(Ay + ks * 32);
                    ar  = mfma16(avh, *(const half8*)(wb + (0 * 16 + ks) * 1024), ar);
                    az  = mfma16(avh, *(const half8*)(wb + (1 * 16 + ks) * 1024), az);
                    anh = mfma16(avh, *(const half8*)(wb + (2 * 16 + ks) * 1024), anh);
                    ar  = mfma16(avy, *(const half8*)(wih + (size_t)(0 * 32 + ks) * 512), ar);
                    az  = mfma16(avy, *(const half8*)(wih + (size_t)(1 * 32 + ks) * 512), az);
                    ani = mfma16(avy, *(const half8*)(wih + (size_t)(2 * 32 + ks) * 512), ani);
                }
#pragma unroll
                for (int ks = 0; ks < 16; ++ks) {      // K-hi: streamed w_hh + w_ih
                    half8 avh = *(const half8*)(Ah + 512 + ks * 32);
                    half8 avy = *(const half8*)(Ay + 512 + ks * 32);
                    ar  = mfma16(avh, *(const half8*)(whh_hi + (size_t)(0 * 16 + ks) * 512), ar);
                    az  = mfma16(avh, *(const half8*)(whh_hi + (size_t)(1 * 16 + ks) * 512), az);
                    anh = mfma16(avh, *(const half8*)(whh_hi + (size_t)(2 * 16 + ks) * 512), anh);
                    ar  = mfma16(avy, *(const half8*)(wih + (size_t)(0 * 32 + 16 + ks) * 512), ar);
                    az  = mfma16(avy, *(const half8*)(wih + (size_t)(1 * 32 + 16 + ks) * 512), az);
                    ani = mfma16(avy, *(const half8*)(wih + (size_t)(2 * 32 + 16 + ks) * 512), ani);
                }
            }

            // epilogue (b_hh_n inside r*(...)); h32 is block-local
            const float* h32o = a.h32 + ((size_t)(layer * 2 + pr)) * BB * HH;
            float*   h32n = a.h32 + ((size_t)(layer * 2 + pw)) * BB * HH;
            _Float16* h16n = a.h16 + ((size_t)(layer * 2 + pw)) * BB * HH;
#pragma unroll
            for (int i = 0; i < 4; ++i) {
                int brow = row0 + lq * 4 + i;   // C/D: row=(lane>>4)*4+i, col=lane&15
                float rg = 1.f / (1.f + expf(-(ar[i] + bir + bhr)));
                float zg = 1.f / (1.f + expf(-(az[i] + biz + bhz)));
                float ng = tanhf(ani[i] + bin + rg * (anh[i] + bhn));
                float hold = h32o[(size_t)brow * HH + j];
                float hnew = (1.f - zg) * ng + zg * hold;
                h32n[(size_t)brow * HH + j] = hnew;
                h16n[(size_t)brow * HH + j] = (_Float16)hnew;
                if (layer == 2) a.y2[(size_t)t * BB * HH + (size_t)brow * HH + j] = (_Float16)hnew;
                if (t == TT - 1) a.out_h[((size_t)layer * BB + brow) * HH + j] = hnew;
            }
        }

        // ---- grid barrier: monotone epoch counter ----
        __syncthreads();                       // drains this block's stores (vmcnt before s_barrier)
        if (tid == 0) {
            __hip_atomic_fetch_add(a.bar, 1u, __ATOMIC_RELEASE, __HIP_MEMORY_SCOPE_AGENT);
            const unsigned target = (unsigned)(s + 1) * NBLK;
            while (__hip_atomic_load(a.bar, __ATOMIC_RELAXED, __HIP_MEMORY_SCOPE_AGENT) < target)
                __builtin_amdgcn_s_sleep(2);
            (void)__hip_atomic_load(a.bar, __ATOMIC_ACQUIRE, __HIP_MEMORY_SCOPE_AGENT);
        }
        __syncthreads();
    }
}

// y = y_l2 @ fc_w^T + fc_b. M=32768, N=256, K=1024. Wave: 16 rows x 8 col-tiles.
__global__ __launch_bounds__(256) void fc_kernel(const _Float16* __restrict__ y,
                                                 const _Float16* __restrict__ w,
                                                 const float* __restrict__ bias,
                                                 float* __restrict__ out) {
    const int wid = (blockIdx.x << 2) + (threadIdx.x >> 6);   // 0..4095
    const int lane = threadIdx.x & 63;
    const int mt = wid >> 1;          // 0..2047
    const int no = (wid & 1) * 8;     // col-tile offset
    const int lr = lane & 15, lq = lane >> 4;
    const _Float16* Ar = y + (size_t)(mt * 16 + lr) * HH + lq * 8;
    floatx4 acc[8] = {};
    for (int k = 0; k < HH; k += 32) {
        half8 av = *(const half8*)(Ar + k);
#pragma unroll
        for (int i = 0; i < 8; ++i) {
            const _Float16* Br = w + (size_t)((no + i) * 16 + lr) * HH + lq * 8 + k;
            acc[i] = mfma16(av, *(const half8*)Br, acc[i]);
        }
    }
#pragma unroll
    for (int i = 0; i < 8; ++i) {
        float b = bias[(no + i) * 16 + lr];
#pragma unroll
        for (int q = 0; q < 4; ++q)
            out[(size_t)(mt * 16 + lq * 4 + q) * OO + (no + i) * 16 + lr] = acc[i][q] + b;
    }
}

extern "C" void kernel_launch(void* const* d_in, const int* in_sizes, int n_in,
                              void* d_out, int out_size, void* d_ws, size_t ws_size,
                              hipStream_t stream) {
    const float* x    = (const float*)d_in[0];
    const float* h0   = (const float*)d_in[1];
    const float* fc_w = (const float*)d_in[2];
    const float* fc_b = (const float*)d_in[3];
    const float* wih[3]; const float* whh[3]; const float* bih[3]; const float* bhh[3];
    for (int l = 0; l < 3; ++l) {
        wih[l] = (const float*)d_in[4 + l * 4 + 0];
        whh[l] = (const float*)d_in[4 + l * 4 + 1];
        bih[l] = (const float*)d_in[4 + l * 4 + 2];
        bhh[l] = (const float*)d_in[4 + l * 4 + 3];
    }

    // ---- carve workspace ----
    char* p = (char*)d_ws;
    auto alloc = [&](size_t bytes) {
        char* q = p;
        p += (bytes + 255) & ~(size_t)255;
        return q;
    };
    _Float16* x16 = (_Float16*)alloc((size_t)TT * BB * II * 2);
    _Float16* y2  = (_Float16*)alloc((size_t)TT * BB * HH * 2);
    _Float16* whh_lo[3]; _Float16* whh_hi[3];
    for (int l = 0; l < 3; ++l) whh_lo[l] = (_Float16*)alloc((size_t)64 * 24576 * 2);
    for (int l = 0; l < 3; ++l) whh_hi[l] = (_Float16*)alloc((size_t)64 * 24576 * 2);
    _Float16* wihf[3];
    wihf[0] = (_Float16*)alloc((size_t)3 * HH * II * 2);
    wihf[1] = (_Float16*)alloc((size_t)3 * HH * HH * 2);
    wihf[2] = (_Float16*)alloc((size_t)3 * HH * HH * 2);
    _Float16* fcw16 = (_Float16*)alloc((size_t)OO * HH * 2);
    float* h32 = (float*)alloc((size_t)LL * 2 * BB * HH * 4);
    _Float16* h16 = (_Float16*)alloc((size_t)LL * 2 * BB * HH * 2);
    unsigned* bar = (unsigned*)alloc(256);
    if ((size_t)(p - (char*)d_ws) > ws_size) return;

    // ---- prep: casts, fragment reorders, state init (+ barrier reset) ----
    cast_f32_f16<<<(TT * BB * II + 255) / 256, 256, 0, stream>>>(x, x16, TT * BB * II);
    cast_f32_f16<<<(OO * HH + 255) / 256, 256, 0, stream>>>(fc_w, fcw16, OO * HH);
    for (int l = 0; l < 3; ++l) {
        frag_reorder<<<768, 256, 0, stream>>>(whh[l], whh_lo[l], HH, 16, 0);
        frag_reorder<<<768, 256, 0, stream>>>(whh[l], whh_hi[l], HH, 16, 512);
    }
    frag_reorder<<<384, 256, 0, stream>>>(wih[0], wihf[0], II, 8, 0);
    frag_reorder<<<1536, 256, 0, stream>>>(wih[1], wihf[1], HH, 32, 0);
    frag_reorder<<<1536, 256, 0, stream>>>(wih[2], wihf[2], HH, 32, 0);
    init_h<<<768, 256, 0, stream>>>(h0, h32, h16, bar);

    // ---- persistent recurrent kernel (plain launch, manual grid barrier) ----
    PArgs a;
    a.x16 = x16;
    for (int l = 0; l < 3; ++l) {
        a.whh_lo[l] = whh_lo[l];
        a.whh_hi[l] = whh_hi[l];
        a.wih[l] = wihf[l];
        a.bih[l] = bih[l];
        a.bhh[l] = bhh[l];
    }
    a.h32 = h32; a.h16 = h16; a.y2 = y2;
    a.out_h = (float*)d_out + (size_t)TT * BB * OO;
    a.bar = bar;
    gru_persistent<<<NBLK, 256, 0, stream>>>(a);

    // ---- final FC ----
    fc_kernel<<<1024, 256, 0, stream>>>(y2, fcw16, fc_b, (float*)d_out);
}

// Round 4
// 21714.940 us; speedup vs baseline: 1.0803x; 1.0803x over previous
//
#include <hip/hip_runtime.h>
#include <cstdint>
#include <cstddef>

// GRU: T=512, B=64, I=256, H=1024, O=256, L=3
#define TT 512
#define BB 64
#define II 256
#define HH 1024
#define OO 256
#define LL 3
#define NBLK 192
#define TSLOTS 513   // T+1 state slots per layer

typedef _Float16 half8 __attribute__((ext_vector_type(8)));
typedef float floatx4 __attribute__((ext_vector_type(4)));
typedef float float4v __attribute__((ext_vector_type(4)));

__device__ __forceinline__ floatx4 mfma16(half8 a, half8 b, floatx4 c) {
    return __builtin_amdgcn_mfma_f32_16x16x32_f16(a, b, c, 0, 0, 0);
}

// load 8 consecutive f32 and convert to half8 (for streaming x)
__device__ __forceinline__ half8 ld_f32x8_cvt(const float* p) {
    float4v a = *(const float4v*)p;
    float4v b = *(const float4v*)(p + 4);
    half8 v;
    v[0]=(_Float16)a[0]; v[1]=(_Float16)a[1]; v[2]=(_Float16)a[2]; v[3]=(_Float16)a[3];
    v[4]=(_Float16)b[0]; v[5]=(_Float16)b[1]; v[6]=(_Float16)b[2]; v[7]=(_Float16)b[3];
    return v;
}

__global__ void cast_f32_f16(const float* __restrict__ in, _Float16* __restrict__ out, int n) {
    int i = blockIdx.x * 256 + threadIdx.x;
    if (i < n) out[i] = (_Float16)in[i];
}

// h32 (both parities) = h0 ; hseq[l][0] = h0 ; bar = 0
__global__ void init_h(const float* __restrict__ h0, float* __restrict__ h32,
                       _Float16* __restrict__ hseq, unsigned* __restrict__ bar) {
    int i = blockIdx.x * 256 + threadIdx.x;
    if (i == 0) *bar = 0u;
    if (i >= LL * BB * HH) return;
    int l = i / (BB * HH);
    int rest = i - l * (BB * HH);
    float v = h0[i];
    h32[((size_t)l * 2 + 0) * BB * HH + rest] = v;
    h32[((size_t)l * 2 + 1) * BB * HH + rest] = v;
    hseq[((size_t)l * TSLOTS) * BB * HH + rest] = (_Float16)v;
}

// Reorder weight [3H][K] (f32) into MFMA B-fragment order (f16).
// chunk idx = ((jb*3 + g)*nks + ks)*64 + lane; chunk = 8 halfs =
// W[g*H + jb*16 + (lane&15)][kcol0 + ks*32 + (lane>>4)*8 .. +8)
__global__ void frag_reorder(const float* __restrict__ src, _Float16* __restrict__ dst,
                             int K, int nks, int kcol0) {
    int idx = blockIdx.x * 256 + threadIdx.x;
    int total = 64 * 3 * nks * 64;
    if (idx >= total) return;
    int lane = idx & 63;
    int r = idx >> 6;
    int ks = r % nks; r /= nks;
    int g = r % 3;
    int jb = r / 3;
    int row = g * HH + jb * 16 + (lane & 15);
    int col = kcol0 + ks * 32 + (lane >> 4) * 8;
    const float* s8 = src + (size_t)row * K + col;
    half8 v;
#pragma unroll
    for (int i = 0; i < 8; ++i) v[i] = (_Float16)s8[i];
    *(half8*)(dst + (size_t)idx * 8) = v;
}

struct PArgs {
    const float* x;              // [T][B][I] f32 (streamed + converted in-kernel)
    const _Float16* whh_hi[3];   // frag order, nks=16, K in [512,1024)
    const _Float16* wih[3];      // frag order; [0]: nks=8 (K=256), [1,2]: nks=32
    const float* whh_src[3];     // f32 [3H][H], for one-time LDS preload (K-lo half)
    const float* bih[3];
    const float* bhh[3];
    _Float16* hseq;              // [L][TSLOTS][B][H] write-once state sequence
    float* h32;                  // [L][2][B][H] fp32 master (parity dbuf, block-local)
    float* out_h;                // d_out + T*B*O
    unsigned* bar;               // epoch barrier counter
};

// Persistent pipelined GRU. 192 blocks x 256 threads (plain launch).
// block = (layer = bid>>6, jb = bid&63 -> cols jb*16..+16).
// LDS: K-lo half of w_hh slice (48KB) + 2KB transpose tile.
__global__ __launch_bounds__(256, 1) void gru_persistent(PArgs a) {
    __shared__ char lds[49152];
    __shared__ _Float16 ht[BB * 16];     // epilogue transpose tile
    const int layer = blockIdx.x >> 6;
    const int jb = blockIdx.x & 63;
    const int tid = threadIdx.x;
    const int lane = tid & 63;
    const int wv = tid >> 6;
    const int lr = lane & 15, lq = lane >> 4;
    const int row0 = wv << 4;
    const int j = (jb << 4) + lr;

    const _Float16* whh_hi = a.whh_hi[layer] + (size_t)jb * 24576 + (size_t)lane * 8;
    const int wih_nks = (layer == 0) ? 8 : 32;
    const _Float16* wih = a.wih[layer] + (size_t)jb * (size_t)(3 * wih_nks * 64 * 8)
                          + (size_t)lane * 8;
    const float* bih = a.bih[layer];
    const float* bhh = a.bhh[layer];

    // one-time LDS preload of K-lo w_hh, fragment order, straight from f32 source
    {
        const float* wsrc = a.whh_src[layer];
        for (int c = tid; c < 3072; c += 256) {
            int lc = c & 63;
            int r = c >> 6;
            int ks = r & 15;
            int g = r >> 4;
            int row = g * HH + (jb << 4) + (lc & 15);
            int col = (ks << 5) + ((lc >> 4) << 3);
            const float* s8 = wsrc + (size_t)row * HH + col;
            half8 v;
#pragma unroll
            for (int i = 0; i < 8; ++i) v[i] = (_Float16)s8[i];
            *(half8*)(lds + (size_t)c * 16) = v;
        }
    }
    __syncthreads();

    const float bir = bih[j], biz = bih[HH + j], bin = bih[2 * HH + j];
    const float bhr = bhh[j], bhz = bhh[HH + j], bhn = bhh[2 * HH + j];
    const char* wb = lds + (size_t)lane * 16;

    for (int s = 0; s < TT + LL - 1; ++s) {
        const int t = s - layer;
        if (t >= 0 && t < TT) {
            const int pr = (s + 1) & 1, pw = s & 1;
            floatx4 ar{0.f,0.f,0.f,0.f}, az{0.f,0.f,0.f,0.f};
            floatx4 ani{0.f,0.f,0.f,0.f}, anh{0.f,0.f,0.f,0.f};
            // own-layer prev state (written at superstep s-1 by same-layer blocks)
            const _Float16* Ah = a.hseq + ((size_t)layer * TSLOTS + t) * BB * HH
                                 + (size_t)(row0 + lr) * HH + lq * 8;

            if (layer == 0) {
                const float* Ax = a.x + (size_t)t * BB * II + (size_t)(row0 + lr) * II + lq * 8;
#pragma unroll
                for (int ks = 0; ks < 8; ++ks) {       // x-side (f32 streamed + cvt)
                    half8 av = ld_f32x8_cvt(Ax + ks * 32);
                    ar  = mfma16(av, *(const half8*)(wih + (size_t)(0 * 8 + ks) * 512), ar);
                    az  = mfma16(av, *(const half8*)(wih + (size_t)(1 * 8 + ks) * 512), az);
                    ani = mfma16(av, *(const half8*)(wih + (size_t)(2 * 8 + ks) * 512), ani);
                }
#pragma unroll
                for (int ks = 0; ks < 16; ++ks) {      // h-side K-lo from LDS
                    half8 av = *(const half8*)(Ah + ks * 32);
                    ar  = mfma16(av, *(const half8*)(wb + (0 * 16 + ks) * 1024), ar);
                    az  = mfma16(av, *(const half8*)(wb + (1 * 16 + ks) * 1024), az);
                    anh = mfma16(av, *(const half8*)(wb + (2 * 16 + ks) * 1024), anh);
                }
#pragma unroll
                for (int ks = 0; ks < 16; ++ks) {      // h-side K-hi streamed (L2-hot)
                    half8 av = *(const half8*)(Ah + 512 + ks * 32);
                    ar  = mfma16(av, *(const half8*)(whh_hi + (size_t)(0 * 16 + ks) * 512), ar);
                    az  = mfma16(av, *(const half8*)(whh_hi + (size_t)(1 * 16 + ks) * 512), az);
                    anh = mfma16(av, *(const half8*)(whh_hi + (size_t)(2 * 16 + ks) * 512), anh);
                }
            } else {
                // prev-layer output at time t (written at superstep s-1)
                const _Float16* Ay = a.hseq + ((size_t)(layer - 1) * TSLOTS + (t + 1)) * BB * HH
                                     + (size_t)(row0 + lr) * HH + lq * 8;
#pragma unroll
                for (int ks = 0; ks < 16; ++ks) {      // K-lo: LDS w_hh + streamed w_ih
                    half8 avh = *(const half8*)(Ah + ks * 32);
                    half8 avy = *(const half8*)(Ay + ks * 32);
                    ar  = mfma16(avh, *(const half8*)(wb + (0 * 16 + ks) * 1024), ar);
                    az  = mfma16(avh, *(const half8*)(wb + (1 * 16 + ks) * 1024), az);
                    anh = mfma16(avh, *(const half8*)(wb + (2 * 16 + ks) * 1024), anh);
                    ar  = mfma16(avy, *(const half8*)(wih + (size_t)(0 * 32 + ks) * 512), ar);
                    az  = mfma16(avy, *(const half8*)(wih + (size_t)(1 * 32 + ks) * 512), az);
                    ani = mfma16(avy, *(const half8*)(wih + (size_t)(2 * 32 + ks) * 512), ani);
                }
#pragma unroll
                for (int ks = 0; ks < 16; ++ks) {      // K-hi: streamed w_hh + w_ih
                    half8 avh = *(const half8*)(Ah + 512 + ks * 32);
                    half8 avy = *(const half8*)(Ay + 512 + ks * 32);
                    ar  = mfma16(avh, *(const half8*)(whh_hi + (size_t)(0 * 16 + ks) * 512), ar);
                    az  = mfma16(avh, *(const half8*)(whh_hi + (size_t)(1 * 16 + ks) * 512), az);
                    anh = mfma16(avh, *(const half8*)(whh_hi + (size_t)(2 * 16 + ks) * 512), anh);
                    ar  = mfma16(avy, *(const half8*)(wih + (size_t)(0 * 32 + 16 + ks) * 512), ar);
                    az  = mfma16(avy, *(const half8*)(wih + (size_t)(1 * 32 + 16 + ks) * 512), az);
                    ani = mfma16(avy, *(const half8*)(wih + (size_t)(2 * 32 + 16 + ks) * 512), ani);
                }
            }

            // epilogue: gates + state update (b_hh_n inside r*(...)); h32 block-local
            const float* h32o = a.h32 + ((size_t)(layer * 2 + pr)) * BB * HH;
            float* h32n = a.h32 + ((size_t)(layer * 2 + pw)) * BB * HH;
#pragma unroll
            for (int i = 0; i < 4; ++i) {
                int brow = row0 + lq * 4 + i;   // C/D: row=(lane>>4)*4+i, col=lane&15
                float rg = 1.f / (1.f + expf(-(ar[i] + bir + bhr)));
                float zg = 1.f / (1.f + expf(-(az[i] + biz + bhz)));
                float ng = tanhf(ani[i] + bin + rg * (anh[i] + bhn));
                float hold = h32o[(size_t)brow * HH + j];
                float hnew = (1.f - zg) * ng + zg * hold;
                h32n[(size_t)brow * HH + j] = hnew;
                ht[brow * 16 + lr] = (_Float16)hnew;
                if (t == TT - 1) a.out_h[((size_t)layer * BB + brow) * HH + j] = hnew;
            }
            __syncthreads();   // ht tile complete
            {
                // publish 64x16 tile to hseq[layer][t+1] as 8B agent-scope stores
                int row = tid >> 2, cg = tid & 3;
                unsigned long long v = *(const unsigned long long*)(ht + row * 16 + cg * 4);
                _Float16* dst = a.hseq + ((size_t)layer * TSLOTS + (t + 1)) * BB * HH
                                + (size_t)row * HH + (jb << 4) + cg * 4;
                __hip_atomic_store((unsigned long long*)dst, v,
                                   __ATOMIC_RELAXED, __HIP_MEMORY_SCOPE_AGENT);
            }
        }

        // ---- relaxed epoch barrier (no cache maintenance) ----
        __syncthreads();   // drains vmcnt: publishes this block's stores to L3
        if (tid == 0) {
            __hip_atomic_fetch_add(a.bar, 1u, __ATOMIC_RELAXED, __HIP_MEMORY_SCOPE_AGENT);
            const unsigned target = (unsigned)(s + 1) * NBLK;
            while (__hip_atomic_load(a.bar, __ATOMIC_RELAXED, __HIP_MEMORY_SCOPE_AGENT) < target)
                __builtin_amdgcn_s_sleep(2);
        }
        __syncthreads();
        __builtin_amdgcn_sched_barrier(0);   // keep next-step loads below the barrier
    }
}

// y = hseq[2][t+1] @ fc_w^T + fc_b. M=32768, N=256, K=1024. Wave: 16 rows x 8 col-tiles.
__global__ __launch_bounds__(256) void fc_kernel(const _Float16* __restrict__ hseq,
                                                 const _Float16* __restrict__ w,
                                                 const float* __restrict__ bias,
                                                 float* __restrict__ out) {
    const int wid = (blockIdx.x << 2) + (threadIdx.x >> 6);   // 0..4095
    const int lane = threadIdx.x & 63;
    const int mt = wid >> 1;          // 0..2047
    const int no = (wid & 1) * 8;     // col-tile offset
    const int lr = lane & 15, lq = lane >> 4;
    // global row of layer-2 slot (t+1): 2*TSLOTS*BB + 64 + m
    const _Float16* Ar = hseq + ((size_t)2 * TSLOTS * BB + BB + (size_t)(mt * 16 + lr)) * HH
                         + lq * 8;
    floatx4 acc[8] = {};
    for (int k = 0; k < HH; k += 32) {
        half8 av = *(const half8*)(Ar + k);
#pragma unroll
        for (int i = 0; i < 8; ++i) {
            const _Float16* Br = w + (size_t)((no + i) * 16 + lr) * HH + lq * 8 + k;
            acc[i] = mfma16(av, *(const half8*)Br, acc[i]);
        }
    }
#pragma unroll
    for (int i = 0; i < 8; ++i) {
        float b = bias[(no + i) * 16 + lr];
#pragma unroll
        for (int q = 0; q < 4; ++q)
            out[(size_t)(mt * 16 + lq * 4 + q) * OO + (no + i) * 16 + lr] = acc[i][q] + b;
    }
}

extern "C" void kernel_launch(void* const* d_in, const int* in_sizes, int n_in,
                              void* d_out, int out_size, void* d_ws, size_t ws_size,
                              hipStream_t stream) {
    const float* x    = (const float*)d_in[0];
    const float* h0   = (const float*)d_in[1];
    const float* fc_w = (const float*)d_in[2];
    const float* fc_b = (const float*)d_in[3];
    const float* wih[3]; const float* whh[3]; const float* bih[3]; const float* bhh[3];
    for (int l = 0; l < 3; ++l) {
        wih[l] = (const float*)d_in[4 + l * 4 + 0];
        whh[l] = (const float*)d_in[4 + l * 4 + 1];
        bih[l] = (const float*)d_in[4 + l * 4 + 2];
        bhh[l] = (const float*)d_in[4 + l * 4 + 3];
    }

    // ---- carve workspace (~227 MB) ----
    char* p = (char*)d_ws;
    auto alloc = [&](size_t bytes) {
        char* q = p;
        p += (bytes + 255) & ~(size_t)255;
        return q;
    };
    _Float16* hseq = (_Float16*)alloc((size_t)LL * TSLOTS * BB * HH * 2);
    _Float16* whh_hi[3];
    for (int l = 0; l < 3; ++l) whh_hi[l] = (_Float16*)alloc((size_t)64 * 24576 * 2);
    _Float16* wihf[3];
    wihf[0] = (_Float16*)alloc((size_t)3 * HH * II * 2);
    wihf[1] = (_Float16*)alloc((size_t)3 * HH * HH * 2);
    wihf[2] = (_Float16*)alloc((size_t)3 * HH * HH * 2);
    _Float16* fcw16 = (_Float16*)alloc((size_t)OO * HH * 2);
    float* h32 = (float*)alloc((size_t)LL * 2 * BB * HH * 4);
    unsigned* bar = (unsigned*)alloc(256);
    if ((size_t)(p - (char*)d_ws) > ws_size) return;

    // ---- prep: fragment reorders, fc cast, state init (+ barrier reset) ----
    cast_f32_f16<<<(OO * HH + 255) / 256, 256, 0, stream>>>(fc_w, fcw16, OO * HH);
    for (int l = 0; l < 3; ++l)
        frag_reorder<<<768, 256, 0, stream>>>(whh[l], whh_hi[l], HH, 16, 512);
    frag_reorder<<<384, 256, 0, stream>>>(wih[0], wihf[0], II, 8, 0);
    frag_reorder<<<1536, 256, 0, stream>>>(wih[1], wihf[1], HH, 32, 0);
    frag_reorder<<<1536, 256, 0, stream>>>(wih[2], wihf[2], HH, 32, 0);
    init_h<<<768, 256, 0, stream>>>(h0, h32, hseq, bar);

    // ---- persistent recurrent kernel ----
    PArgs a;
    a.x = x;
    for (int l = 0; l < 3; ++l) {
        a.whh_hi[l] = whh_hi[l];
        a.wih[l] = wihf[l];
        a.whh_src[l] = whh[l];
        a.bih[l] = bih[l];
        a.bhh[l] = bhh[l];
    }
    a.hseq = hseq; a.h32 = h32;
    a.out_h = (float*)d_out + (size_t)TT * BB * OO;
    a.bar = bar;
    gru_persistent<<<NBLK, 256, 0, stream>>>(a);

    // ---- final FC ----
    fc_kernel<<<1024, 256, 0, stream>>>(hseq, fcw16, fc_b, (float*)d_out);
}

// Round 5
// 8686.556 us; speedup vs baseline: 2.7007x; 2.4998x over previous
//
#include <hip/hip_runtime.h>
#include <cstdint>
#include <cstddef>

// GRU: T=512, B=64, I=256, H=1024, O=256, L=3
#define TT 512
#define BB 64
#define II 256
#define HH 1024
#define OO 256
#define LL 3
#define NBLK 192
#define TSLOTS 513            // T+1 state slots per layer
#define DD 2                  // layer pipeline depth
#define SSTEPS (TT + 2*DD + 1) // 517
// LDS layout (bytes)
#define LDS_GI   98304                 // after 96KB whh frags
#define GI_STRIDE 68                   // floats, padded
#define LDS_HT   (98304 + 26112)       // gi = 2*3*16*68*4 = 26112
#define LDS_TOTAL (LDS_HT + 2048)      // + ht 64*16*2 = 126464

typedef _Float16 half8 __attribute__((ext_vector_type(8)));
typedef float floatx4 __attribute__((ext_vector_type(4)));
typedef float float4v __attribute__((ext_vector_type(4)));

__device__ __forceinline__ floatx4 mfma16(half8 a, half8 b, floatx4 c) {
    return __builtin_amdgcn_mfma_f32_16x16x32_f16(a, b, c, 0, 0, 0);
}

__device__ __forceinline__ half8 ld_f32x8_cvt(const float* p) {
    float4v a = *(const float4v*)p;
    float4v b = *(const float4v*)(p + 4);
    half8 v;
    v[0]=(_Float16)a[0]; v[1]=(_Float16)a[1]; v[2]=(_Float16)a[2]; v[3]=(_Float16)a[3];
    v[4]=(_Float16)b[0]; v[5]=(_Float16)b[1]; v[6]=(_Float16)b[2]; v[7]=(_Float16)b[3];
    return v;
}

__global__ void cast_f32_f16(const float* __restrict__ in, _Float16* __restrict__ out, int n) {
    int i = blockIdx.x * 256 + threadIdx.x;
    if (i < n) out[i] = (_Float16)in[i];
}

// h32 (both parities) = h0 ; hseq[l][0] = h0 ; flags/rel = 0
__global__ void init_h(const float* __restrict__ h0, float* __restrict__ h32,
                       _Float16* __restrict__ hseq, unsigned* __restrict__ bararea) {
    int i = blockIdx.x * 256 + threadIdx.x;
    if (i < 256) bararea[i] = 0u;
    if (i >= LL * BB * HH) return;
    int l = i / (BB * HH);
    int rest = i - l * (BB * HH);
    float v = h0[i];
    h32[((size_t)l * 2 + 0) * BB * HH + rest] = v;
    h32[((size_t)l * 2 + 1) * BB * HH + rest] = v;
    hseq[((size_t)l * TSLOTS) * BB * HH + rest] = (_Float16)v;
}

// Reorder w_ih [3H][K] (f32) into MFMA B-fragment order (f16).
__global__ void frag_reorder(const float* __restrict__ src, _Float16* __restrict__ dst,
                             int K, int nks) {
    int idx = blockIdx.x * 256 + threadIdx.x;
    int total = 64 * 3 * nks * 64;
    if (idx >= total) return;
    int lane = idx & 63;
    int r = idx >> 6;
    int ks = r % nks; r /= nks;
    int g = r % 3;
    int jb = r / 3;
    int row = g * HH + jb * 16 + (lane & 15);
    int col = ks * 32 + (lane >> 4) * 8;
    const float* s8 = src + (size_t)row * K + col;
    half8 v;
#pragma unroll
    for (int i = 0; i < 8; ++i) v[i] = (_Float16)s8[i];
    *(half8*)(dst + (size_t)idx * 8) = v;
}

struct PArgs {
    const float* x;              // [T][B][I] f32
    const _Float16* wih[3];      // frag order; [0]: nks=8, [1,2]: nks=32
    const float* whh_src[3];     // f32 [3H][H] for LDS preload
    const float* bih[3];
    const float* bhh[3];
    _Float16* hseq;              // [L][TSLOTS][B][H] write-once state sequence
    float* h32;                  // [L][2][B][H] fp32 master (block-local)
    float* out_h;                // d_out + T*B*O
    unsigned* flags;             // [NBLK] arrival flags
    unsigned* rel;               // release word
};

// Persistent pipelined GRU. 192 blocks x 512 threads (8 waves, 2/SIMD).
// block = (layer = bid>>6, jb = bid&63 -> cols jb*16..+16).
// waves 0-3: recurrent h-side (w_hh fully in LDS) + epilogue (t = s-2*layer-1)
// waves 4-7: gi = input-side projection for t' = s-2*layer (one step ahead)
__global__ __launch_bounds__(512, 2) void gru_persistent(PArgs a) {
    extern __shared__ __align__(16) char lds[];
    float* giL = (float*)(lds + LDS_GI);
    _Float16* ht = (_Float16*)(lds + LDS_HT);
    const int layer = blockIdx.x >> 6;
    const int jb = blockIdx.x & 63;
    const int tid = threadIdx.x;
    const int lane = tid & 63;
    const int wv = tid >> 6;
    const bool isrec = wv < 4;
    const int lr = lane & 15, lq = lane >> 4;
    const int row0 = (wv & 3) << 4;
    const int j = (jb << 4) + lr;

    const int wih_nks = (layer == 0) ? 8 : 32;
    const _Float16* wih = a.wih[layer] + (size_t)jb * (size_t)(3 * wih_nks * 64 * 8)
                          + (size_t)lane * 8;

    // ---- one-time LDS preload: FULL w_hh slice (96KB), fragment order ----
    {
        const float* wsrc = a.whh_src[layer];
        for (int c = tid; c < 6144; c += 512) {
            int lc = c & 63;
            int ks = (c >> 6) & 31;
            int g  = c >> 11;
            int row = g * HH + (jb << 4) + (lc & 15);
            int col = (ks << 5) + ((lc >> 4) << 3);
            const float* s8 = wsrc + (size_t)row * HH + col;
            half8 v;
#pragma unroll
            for (int i = 0; i < 8; ++i) v[i] = (_Float16)s8[i];
            *(half8*)(lds + (size_t)c * 16) = v;
        }
    }
    __syncthreads();

    const float bir = a.bih[layer][j], biz = a.bih[layer][HH + j], bin = a.bih[layer][2 * HH + j];
    const float bhr = a.bhh[layer][j], bhz = a.bhh[layer][HH + j], bhn = a.bhh[layer][2 * HH + j];
    const char* wb = lds + (size_t)lane * 16;

    for (int s = 0; s < SSTEPS; ++s) {
        const int t = s - (2 * layer + 1);             // rec timestep
        const int tp = s - 2 * layer;                  // gi timestep (t+1)
        const bool rec_act = (t >= 0 && t < TT);
        const bool gi_act = (tp >= 0 && tp < TT);
        const int pr = (s + 1) & 1, pw = s & 1;

        if (isrec && rec_act) {
            floatx4 ar{0.f,0.f,0.f,0.f}, az{0.f,0.f,0.f,0.f}, anh{0.f,0.f,0.f,0.f};
            const _Float16* Ah = a.hseq + ((size_t)layer * TSLOTS + t) * BB * HH
                                 + (size_t)(row0 + lr) * HH + lq * 8;
#pragma unroll
            for (int ks = 0; ks < 32; ++ks) {
                half8 av = *(const half8*)(Ah + ks * 32);
                ar  = mfma16(av, *(const half8*)(wb + (0 * 32 + ks) * 1024), ar);
                az  = mfma16(av, *(const half8*)(wb + (1 * 32 + ks) * 1024), az);
                anh = mfma16(av, *(const half8*)(wb + (2 * 32 + ks) * 1024), anh);
            }
            // epilogue: gi from LDS (parity pr), gates, state update
            const float* h32o = a.h32 + ((size_t)(layer * 2 + pr)) * BB * HH;
            float* h32n = a.h32 + ((size_t)(layer * 2 + pw)) * BB * HH;
#pragma unroll
            for (int i2 = 0; i2 < 4; ++i2) {
                int brow = row0 + lq * 4 + i2;
                float gir = giL[((pr * 3 + 0) * 16 + lr) * GI_STRIDE + brow];
                float giz = giL[((pr * 3 + 1) * 16 + lr) * GI_STRIDE + brow];
                float gin = giL[((pr * 3 + 2) * 16 + lr) * GI_STRIDE + brow];
                float rg = 1.f / (1.f + expf(-(ar[i2] + gir + bir + bhr)));
                float zg = 1.f / (1.f + expf(-(az[i2] + giz + biz + bhz)));
                float ng = tanhf(gin + bin + rg * (anh[i2] + bhn));
                float hold = h32o[(size_t)brow * HH + j];
                float hnew = (1.f - zg) * ng + zg * hold;
                h32n[(size_t)brow * HH + j] = hnew;
                ht[brow * 16 + lr] = (_Float16)hnew;
                if (t == TT - 1) a.out_h[((size_t)layer * BB + brow) * HH + j] = hnew;
            }
        }
        if (!isrec && gi_act) {
            floatx4 g0{0.f,0.f,0.f,0.f}, g1{0.f,0.f,0.f,0.f}, g2{0.f,0.f,0.f,0.f};
            if (layer == 0) {
                const float* Ax = a.x + (size_t)tp * BB * II + (size_t)(row0 + lr) * II + lq * 8;
#pragma unroll
                for (int ks = 0; ks < 8; ++ks) {
                    half8 av = ld_f32x8_cvt(Ax + ks * 32);
                    g0 = mfma16(av, *(const half8*)(wih + (size_t)(0 * 8 + ks) * 512), g0);
                    g1 = mfma16(av, *(const half8*)(wih + (size_t)(1 * 8 + ks) * 512), g1);
                    g2 = mfma16(av, *(const half8*)(wih + (size_t)(2 * 8 + ks) * 512), g2);
                }
            } else {
                const _Float16* Ay = a.hseq + ((size_t)(layer - 1) * TSLOTS + (tp + 1)) * BB * HH
                                     + (size_t)(row0 + lr) * HH + lq * 8;
#pragma unroll
                for (int ks = 0; ks < 32; ++ks) {
                    half8 av = *(const half8*)(Ay + ks * 32);
                    g0 = mfma16(av, *(const half8*)(wih + (size_t)(0 * 32 + ks) * 512), g0);
                    g1 = mfma16(av, *(const half8*)(wih + (size_t)(1 * 32 + ks) * 512), g1);
                    g2 = mfma16(av, *(const half8*)(wih + (size_t)(2 * 32 + ks) * 512), g2);
                }
            }
            // write gi to LDS parity pw: [par][gate][col16][row64+pad]
#pragma unroll
            for (int q = 0; q < 4; ++q) {
                int brow = row0 + lq * 4 + q;
                giL[((pw * 3 + 0) * 16 + lr) * GI_STRIDE + brow] = g0[q];
                giL[((pw * 3 + 1) * 16 + lr) * GI_STRIDE + brow] = g1[q];
                giL[((pw * 3 + 2) * 16 + lr) * GI_STRIDE + brow] = g2[q];
            }
        }
        __syncthreads();   // ht + gi tiles complete (block-uniform)

        if (rec_act && tid < 256) {
            // publish 64x16 fp16 tile to hseq[layer][t+1] as 8B agent-scope stores
            int row = tid >> 2, cg = tid & 3;
            unsigned long long v = *(const unsigned long long*)(ht + row * 16 + cg * 4);
            _Float16* dst = a.hseq + ((size_t)layer * TSLOTS + (t + 1)) * BB * HH
                            + (size_t)row * HH + (jb << 4) + cg * 4;
            __hip_atomic_store((unsigned long long*)dst, v,
                               __ATOMIC_RELAXED, __HIP_MEMORY_SCOPE_AGENT);
        }

        // ---- RMW-free epoch barrier ----
        __syncthreads();   // drains vmcnt: all block stores at coherent point
        if (tid == 0)
            __hip_atomic_store(&a.flags[blockIdx.x], (unsigned)(s + 1),
                               __ATOMIC_RELAXED, __HIP_MEMORY_SCOPE_AGENT);
        if (blockIdx.x == 0 && tid < 64) {
            const unsigned need = (unsigned)(s + 1);
            for (;;) {
                bool ok = true;
                for (int i = (int)tid; i < NBLK; i += 64)
                    ok = ok && (__hip_atomic_load(&a.flags[i], __ATOMIC_RELAXED,
                                                  __HIP_MEMORY_SCOPE_AGENT) >= need);
                if (__all(ok)) break;
                __builtin_amdgcn_s_sleep(1);
            }
            if (tid == 0)
                __hip_atomic_store(a.rel, need, __ATOMIC_RELAXED, __HIP_MEMORY_SCOPE_AGENT);
        }
        if (tid == 0) {
            while (__hip_atomic_load(a.rel, __ATOMIC_RELAXED,
                                     __HIP_MEMORY_SCOPE_AGENT) < (unsigned)(s + 1))
                __builtin_amdgcn_s_sleep(1);
        }
        __syncthreads();
        __builtin_amdgcn_sched_barrier(0);   // keep next-step loads below the barrier
    }
}

// y = hseq[2][t+1] @ fc_w^T + fc_b. M=32768, N=256, K=1024.
__global__ __launch_bounds__(256) void fc_kernel(const _Float16* __restrict__ hseq,
                                                 const _Float16* __restrict__ w,
                                                 const float* __restrict__ bias,
                                                 float* __restrict__ out) {
    const int wid = (blockIdx.x << 2) + (threadIdx.x >> 6);   // 0..4095
    const int lane = threadIdx.x & 63;
    const int mt = wid >> 1;
    const int no = (wid & 1) * 8;
    const int lr = lane & 15, lq = lane >> 4;
    const _Float16* Ar = hseq + ((size_t)2 * TSLOTS * BB + BB + (size_t)(mt * 16 + lr)) * HH
                         + lq * 8;
    floatx4 acc[8] = {};
    for (int k = 0; k < HH; k += 32) {
        half8 av = *(const half8*)(Ar + k);
#pragma unroll
        for (int i = 0; i < 8; ++i) {
            const _Float16* Br = w + (size_t)((no + i) * 16 + lr) * HH + lq * 8 + k;
            acc[i] = mfma16(av, *(const half8*)Br, acc[i]);
        }
    }
#pragma unroll
    for (int i = 0; i < 8; ++i) {
        float b = bias[(no + i) * 16 + lr];
#pragma unroll
        for (int q = 0; q < 4; ++q)
            out[(size_t)(mt * 16 + lq * 4 + q) * OO + (no + i) * 16 + lr] = acc[i][q] + b;
    }
}

extern "C" void kernel_launch(void* const* d_in, const int* in_sizes, int n_in,
                              void* d_out, int out_size, void* d_ws, size_t ws_size,
                              hipStream_t stream) {
    const float* x    = (const float*)d_in[0];
    const float* h0   = (const float*)d_in[1];
    const float* fc_w = (const float*)d_in[2];
    const float* fc_b = (const float*)d_in[3];
    const float* wih[3]; const float* whh[3]; const float* bih[3]; const float* bhh[3];
    for (int l = 0; l < 3; ++l) {
        wih[l] = (const float*)d_in[4 + l * 4 + 0];
        whh[l] = (const float*)d_in[4 + l * 4 + 1];
        bih[l] = (const float*)d_in[4 + l * 4 + 2];
        bhh[l] = (const float*)d_in[4 + l * 4 + 3];
    }

    // ---- carve workspace (~212 MB) ----
    char* p = (char*)d_ws;
    auto alloc = [&](size_t bytes) {
        char* q = p;
        p += (bytes + 255) & ~(size_t)255;
        return q;
    };
    _Float16* hseq = (_Float16*)alloc((size_t)LL * TSLOTS * BB * HH * 2);
    _Float16* wihf[3];
    wihf[0] = (_Float16*)alloc((size_t)3 * HH * II * 2);
    wihf[1] = (_Float16*)alloc((size_t)3 * HH * HH * 2);
    wihf[2] = (_Float16*)alloc((size_t)3 * HH * HH * 2);
    _Float16* fcw16 = (_Float16*)alloc((size_t)OO * HH * 2);
    float* h32 = (float*)alloc((size_t)LL * 2 * BB * HH * 4);
    unsigned* bararea = (unsigned*)alloc(1024);
    if ((size_t)(p - (char*)d_ws) > ws_size) return;

    // ---- prep ----
    cast_f32_f16<<<(OO * HH + 255) / 256, 256, 0, stream>>>(fc_w, fcw16, OO * HH);
    frag_reorder<<<384, 256, 0, stream>>>(wih[0], wihf[0], II, 8);
    frag_reorder<<<1536, 256, 0, stream>>>(wih[1], wihf[1], HH, 32);
    frag_reorder<<<1536, 256, 0, stream>>>(wih[2], wihf[2], HH, 32);
    init_h<<<768, 256, 0, stream>>>(h0, h32, hseq, bararea);

    // ---- persistent recurrent kernel (plain launch, 124KB dynamic LDS) ----
    PArgs a;
    a.x = x;
    for (int l = 0; l < 3; ++l) {
        a.wih[l] = wihf[l];
        a.whh_src[l] = whh[l];
        a.bih[l] = bih[l];
        a.bhh[l] = bhh[l];
    }
    a.hseq = hseq; a.h32 = h32;
    a.out_h = (float*)d_out + (size_t)TT * BB * OO;
    a.flags = bararea;
    a.rel = bararea + 224;

    hipFuncSetAttribute((const void*)gru_persistent,
                        hipFuncAttributeMaxDynamicSharedMemorySize, LDS_TOTAL);
    gru_persistent<<<NBLK, 512, LDS_TOTAL, stream>>>(a);

    // ---- final FC ----
    fc_kernel<<<1024, 256, 0, stream>>>(hseq, fcw16, fc_b, (float*)d_out);
}

// Round 6
// 8680.584 us; speedup vs baseline: 2.7025x; 1.0007x over previous
//
#include <hip/hip_runtime.h>
#include <cstdint>
#include <cstddef>

// GRU: T=512, B=64, I=256, H=1024, O=256, L=3
#define TT 512
#define BB 64
#define II 256
#define HH 1024
#define OO 256
#define LL 3
#define NBLK 192
#define TSLOTS 513            // T+1 state slots per layer
#define DD 2                  // layer pipeline depth
#define SSTEPS (TT + 2*DD + 1) // 517
// LDS layout (bytes)
#define LDS_GI   98304                 // after 96KB whh frags
#define GI_STRIDE 68                   // floats, padded
#define LDS_HT   (98304 + 26112)       // gi = 2*3*16*68*4 = 26112
#define LDS_TOTAL (LDS_HT + 2048)      // + ht 64*16*2 = 126464

typedef _Float16 half8 __attribute__((ext_vector_type(8)));
typedef float floatx4 __attribute__((ext_vector_type(4)));
typedef float float4v __attribute__((ext_vector_type(4)));

__device__ __forceinline__ floatx4 mfma16(half8 a, half8 b, floatx4 c) {
    return __builtin_amdgcn_mfma_f32_16x16x32_f16(a, b, c, 0, 0, 0);
}

__device__ __forceinline__ half8 ld_f32x8_cvt(const float* p) {
    float4v a = *(const float4v*)p;
    float4v b = *(const float4v*)(p + 4);
    half8 v;
    v[0]=(_Float16)a[0]; v[1]=(_Float16)a[1]; v[2]=(_Float16)a[2]; v[3]=(_Float16)a[3];
    v[4]=(_Float16)b[0]; v[5]=(_Float16)b[1]; v[6]=(_Float16)b[2]; v[7]=(_Float16)b[3];
    return v;
}

__global__ void cast_f32_f16(const float* __restrict__ in, _Float16* __restrict__ out, int n) {
    int i = blockIdx.x * 256 + threadIdx.x;
    if (i < n) out[i] = (_Float16)in[i];
}

// h32 (both parities) = h0 ; hseq[l][0] = h0 ; flags/rel = 0
__global__ void init_h(const float* __restrict__ h0, float* __restrict__ h32,
                       _Float16* __restrict__ hseq, unsigned* __restrict__ bararea) {
    int i = blockIdx.x * 256 + threadIdx.x;
    if (i < 256) bararea[i] = 0u;
    if (i >= LL * BB * HH) return;
    int l = i / (BB * HH);
    int rest = i - l * (BB * HH);
    float v = h0[i];
    h32[((size_t)l * 2 + 0) * BB * HH + rest] = v;
    h32[((size_t)l * 2 + 1) * BB * HH + rest] = v;
    hseq[((size_t)l * TSLOTS) * BB * HH + rest] = (_Float16)v;
}

// Reorder w_ih [3H][K] (f32) into MFMA B-fragment order (f16).
__global__ void frag_reorder(const float* __restrict__ src, _Float16* __restrict__ dst,
                             int K, int nks) {
    int idx = blockIdx.x * 256 + threadIdx.x;
    int total = 64 * 3 * nks * 64;
    if (idx >= total) return;
    int lane = idx & 63;
    int r = idx >> 6;
    int ks = r % nks; r /= nks;
    int g = r % 3;
    int jb = r / 3;
    int row = g * HH + jb * 16 + (lane & 15);
    int col = ks * 32 + (lane >> 4) * 8;
    const float* s8 = src + (size_t)row * K + col;
    half8 v;
#pragma unroll
    for (int i = 0; i < 8; ++i) v[i] = (_Float16)s8[i];
    *(half8*)(dst + (size_t)idx * 8) = v;
}

struct PArgs {
    const float* x;              // [T][B][I] f32
    const _Float16* wih[3];      // frag order; [0]: nks=8, [1,2]: nks=32
    const float* whh_src[3];     // f32 [3H][H] for LDS preload
    const float* bih[3];
    const float* bhh[3];
    _Float16* hseq;              // [L][TSLOTS][B][H] write-once state sequence
    float* h32;                  // [L][2][B][H] fp32 master (block-local)
    float* out_h;                // d_out + T*B*O
    unsigned* flags;             // [NBLK] arrival flags
    unsigned* rel;               // release word
};

// Persistent pipelined GRU. 192 blocks x 512 threads (8 waves, 2/SIMD).
// block = (layer = bid>>6, jb = bid&63 -> cols jb*16..+16).
// waves 0-3: recurrent h-side (w_hh fully in LDS) + epilogue (t = s-2*layer-1)
// waves 4-7: gi = input-side projection for t' = s-2*layer (one step ahead)
__global__ __launch_bounds__(512, 2) void gru_persistent(PArgs a) {
    extern __shared__ __align__(16) char lds[];
    float* giL = (float*)(lds + LDS_GI);
    _Float16* ht = (_Float16*)(lds + LDS_HT);
    const int layer = blockIdx.x >> 6;
    const int jb = blockIdx.x & 63;
    const int tid = threadIdx.x;
    const int lane = tid & 63;
    const int wv = tid >> 6;
    const bool isrec = wv < 4;
    const int lr = lane & 15, lq = lane >> 4;
    const int row0 = (wv & 3) << 4;
    const int j = (jb << 4) + lr;

    const int wih_nks = (layer == 0) ? 8 : 32;
    const _Float16* wih = a.wih[layer] + (size_t)jb * (size_t)(3 * wih_nks * 64 * 8)
                          + (size_t)lane * 8;

    // ---- one-time LDS preload: FULL w_hh slice (96KB), fragment order ----
    {
        const float* wsrc = a.whh_src[layer];
        for (int c = tid; c < 6144; c += 512) {
            int lc = c & 63;
            int ks = (c >> 6) & 31;
            int g  = c >> 11;
            int row = g * HH + (jb << 4) + (lc & 15);
            int col = (ks << 5) + ((lc >> 4) << 3);
            const float* s8 = wsrc + (size_t)row * HH + col;
            half8 v;
#pragma unroll
            for (int i = 0; i < 8; ++i) v[i] = (_Float16)s8[i];
            *(half8*)(lds + (size_t)c * 16) = v;
        }
    }
    __syncthreads();

    const float bir = a.bih[layer][j], biz = a.bih[layer][HH + j], bin = a.bih[layer][2 * HH + j];
    const float bhr = a.bhh[layer][j], bhz = a.bhh[layer][HH + j], bhn = a.bhh[layer][2 * HH + j];
    const char* wb = lds + (size_t)lane * 16;

    for (int s = 0; s < SSTEPS; ++s) {
        const int t = s - (2 * layer + 1);             // rec timestep
        const int tp = s - 2 * layer;                  // gi timestep (t+1)
        const bool rec_act = (t >= 0 && t < TT);
        const bool gi_act = (tp >= 0 && tp < TT);
        const int pr = (s + 1) & 1, pw = s & 1;

        if (isrec && rec_act) {
            floatx4 ar{0.f,0.f,0.f,0.f}, az{0.f,0.f,0.f,0.f}, anh{0.f,0.f,0.f,0.f};
            const _Float16* Ah = a.hseq + ((size_t)layer * TSLOTS + t) * BB * HH
                                 + (size_t)(row0 + lr) * HH + lq * 8;
#pragma unroll
            for (int ks = 0; ks < 32; ++ks) {
                half8 av = *(const half8*)(Ah + ks * 32);
                ar  = mfma16(av, *(const half8*)(wb + (0 * 32 + ks) * 1024), ar);
                az  = mfma16(av, *(const half8*)(wb + (1 * 32 + ks) * 1024), az);
                anh = mfma16(av, *(const half8*)(wb + (2 * 32 + ks) * 1024), anh);
            }
            // epilogue: gi from LDS (parity pr), gates, state update
            const float* h32o = a.h32 + ((size_t)(layer * 2 + pr)) * BB * HH;
            float* h32n = a.h32 + ((size_t)(layer * 2 + pw)) * BB * HH;
#pragma unroll
            for (int i2 = 0; i2 < 4; ++i2) {
                int brow = row0 + lq * 4 + i2;
                float gir = giL[((pr * 3 + 0) * 16 + lr) * GI_STRIDE + brow];
                float giz = giL[((pr * 3 + 1) * 16 + lr) * GI_STRIDE + brow];
                float gin = giL[((pr * 3 + 2) * 16 + lr) * GI_STRIDE + brow];
                float rg = 1.f / (1.f + expf(-(ar[i2] + gir + bir + bhr)));
                float zg = 1.f / (1.f + expf(-(az[i2] + giz + biz + bhz)));
                float ng = tanhf(gin + bin + rg * (anh[i2] + bhn));
                float hold = h32o[(size_t)brow * HH + j];
                float hnew = (1.f - zg) * ng + zg * hold;
                h32n[(size_t)brow * HH + j] = hnew;
                ht[brow * 16 + lr] = (_Float16)hnew;
                if (t == TT - 1) a.out_h[((size_t)layer * BB + brow) * HH + j] = hnew;
            }
        }
        if (!isrec && gi_act) {
            floatx4 g0{0.f,0.f,0.f,0.f}, g1{0.f,0.f,0.f,0.f}, g2{0.f,0.f,0.f,0.f};
            if (layer == 0) {
                const float* Ax = a.x + (size_t)tp * BB * II + (size_t)(row0 + lr) * II + lq * 8;
#pragma unroll
                for (int ks = 0; ks < 8; ++ks) {
                    half8 av = ld_f32x8_cvt(Ax + ks * 32);
                    g0 = mfma16(av, *(const half8*)(wih + (size_t)(0 * 8 + ks) * 512), g0);
                    g1 = mfma16(av, *(const half8*)(wih + (size_t)(1 * 8 + ks) * 512), g1);
                    g2 = mfma16(av, *(const half8*)(wih + (size_t)(2 * 8 + ks) * 512), g2);
                }
            } else {
                const _Float16* Ay = a.hseq + ((size_t)(layer - 1) * TSLOTS + (tp + 1)) * BB * HH
                                     + (size_t)(row0 + lr) * HH + lq * 8;
#pragma unroll
                for (int ks = 0; ks < 32; ++ks) {
                    half8 av = *(const half8*)(Ay + ks * 32);
                    g0 = mfma16(av, *(const half8*)(wih + (size_t)(0 * 32 + ks) * 512), g0);
                    g1 = mfma16(av, *(const half8*)(wih + (size_t)(1 * 32 + ks) * 512), g1);
                    g2 = mfma16(av, *(const half8*)(wih + (size_t)(2 * 32 + ks) * 512), g2);
                }
            }
            // write gi to LDS parity pw: [par][gate][col16][row64+pad]
#pragma unroll
            for (int q = 0; q < 4; ++q) {
                int brow = row0 + lq * 4 + q;
                giL[((pw * 3 + 0) * 16 + lr) * GI_STRIDE + brow] = g0[q];
                giL[((pw * 3 + 1) * 16 + lr) * GI_STRIDE + brow] = g1[q];
                giL[((pw * 3 + 2) * 16 + lr) * GI_STRIDE + brow] = g2[q];
            }
        }
        __syncthreads();   // ht + gi tiles complete (block-uniform)

        if (rec_act && tid < 256) {
            // publish 64x16 fp16 tile to hseq[layer][t+1] as 8B agent-scope stores
            int row = tid >> 2, cg = tid & 3;
            unsigned long long v = *(const unsigned long long*)(ht + row * 16 + cg * 4);
            _Float16* dst = a.hseq + ((size_t)layer * TSLOTS + (t + 1)) * BB * HH
                            + (size_t)row * HH + (jb << 4) + cg * 4;
            __hip_atomic_store((unsigned long long*)dst, v,
                               __ATOMIC_RELAXED, __HIP_MEMORY_SCOPE_AGENT);
        }

        // ---- RMW-free epoch barrier ----
        __syncthreads();   // drains vmcnt: all block stores at coherent point
        if (tid == 0)
            __hip_atomic_store(&a.flags[blockIdx.x], (unsigned)(s + 1),
                               __ATOMIC_RELAXED, __HIP_MEMORY_SCOPE_AGENT);
        if (blockIdx.x == 0 && tid < 64) {
            const unsigned need = (unsigned)(s + 1);
            for (;;) {
                bool ok = true;
                for (int i = (int)tid; i < NBLK; i += 64)
                    ok = ok && (__hip_atomic_load(&a.flags[i], __ATOMIC_RELAXED,
                                                  __HIP_MEMORY_SCOPE_AGENT) >= need);
                if (__all(ok)) break;
                __builtin_amdgcn_s_sleep(1);
            }
            if (tid == 0)
                __hip_atomic_store(a.rel, need, __ATOMIC_RELAXED, __HIP_MEMORY_SCOPE_AGENT);
        }
        if (tid == 0) {
            while (__hip_atomic_load(a.rel, __ATOMIC_RELAXED,
                                     __HIP_MEMORY_SCOPE_AGENT) < (unsigned)(s + 1))
                __builtin_amdgcn_s_sleep(1);
        }
        __syncthreads();
        __builtin_amdgcn_sched_barrier(0);   // keep next-step loads below the barrier
    }
}

// y = hseq[2][t+1] @ fc_w^T + fc_b. M=32768, N=256, K=1024.
__global__ __launch_bounds__(256) void fc_kernel(const _Float16* __restrict__ hseq,
                                                 const _Float16* __restrict__ w,
                                                 const float* __restrict__ bias,
                                                 float* __restrict__ out) {
    const int wid = (blockIdx.x << 2) + (threadIdx.x >> 6);   // 0..4095
    const int lane = threadIdx.x & 63;
    const int mt = wid >> 1;
    const int no = (wid & 1) * 8;
    const int lr = lane & 15, lq = lane >> 4;
    const _Float16* Ar = hseq + ((size_t)2 * TSLOTS * BB + BB + (size_t)(mt * 16 + lr)) * HH
                         + lq * 8;
    floatx4 acc[8] = {};
    for (int k = 0; k < HH; k += 32) {
        half8 av = *(const half8*)(Ar + k);
#pragma unroll
        for (int i = 0; i < 8; ++i) {
            const _Float16* Br = w + (size_t)((no + i) * 16 + lr) * HH + lq * 8 + k;
            acc[i] = mfma16(av, *(const half8*)Br, acc[i]);
        }
    }
#pragma unroll
    for (int i = 0; i < 8; ++i) {
        float b = bias[(no + i) * 16 + lr];
#pragma unroll
        for (int q = 0; q < 4; ++q)
            out[(size_t)(mt * 16 + lq * 4 + q) * OO + (no + i) * 16 + lr] = acc[i][q] + b;
    }
}

extern "C" void kernel_launch(void* const* d_in, const int* in_sizes, int n_in,
                              void* d_out, int out_size, void* d_ws, size_t ws_size,
                              hipStream_t stream) {
    const float* x    = (const float*)d_in[0];
    const float* h0   = (const float*)d_in[1];
    const float* fc_w = (const float*)d_in[2];
    const float* fc_b = (const float*)d_in[3];
    const float* wih[3]; const float* whh[3]; const float* bih[3]; const float* bhh[3];
    for (int l = 0; l < 3; ++l) {
        wih[l] = (const float*)d_in[4 + l * 4 + 0];
        whh[l] = (const float*)d_in[4 + l * 4 + 1];
        bih[l] = (const float*)d_in[4 + l * 4 + 2];
        bhh[l] = (const float*)d_in[4 + l * 4 + 3];
    }

    // ---- carve workspace (~212 MB) ----
    char* p = (char*)d_ws;
    auto alloc = [&](size_t bytes) {
        char* q = p;
        p += (bytes + 255) & ~(size_t)255;
        return q;
    };
    _Float16* hseq = (_Float16*)alloc((size_t)LL * TSLOTS * BB * HH * 2);
    _Float16* wihf[3];
    wihf[0] = (_Float16*)alloc((size_t)3 * HH * II * 2);
    wihf[1] = (_Float16*)alloc((size_t)3 * HH * HH * 2);
    wihf[2] = (_Float16*)alloc((size_t)3 * HH * HH * 2);
    _Float16* fcw16 = (_Float16*)alloc((size_t)OO * HH * 2);
    float* h32 = (float*)alloc((size_t)LL * 2 * BB * HH * 4);
    unsigned* bararea = (unsigned*)alloc(1024);
    if ((size_t)(p - (char*)d_ws) > ws_size) return;

    // ---- prep ----
    cast_f32_f16<<<(OO * HH + 255) / 256, 256, 0, stream>>>(fc_w, fcw16, OO * HH);
    frag_reorder<<<384, 256, 0, stream>>>(wih[0], wihf[0], II, 8);
    frag_reorder<<<1536, 256, 0, stream>>>(wih[1], wihf[1], HH, 32);
    frag_reorder<<<1536, 256, 0, stream>>>(wih[2], wihf[2], HH, 32);
    init_h<<<768, 256, 0, stream>>>(h0, h32, hseq, bararea);

    // ---- persistent recurrent kernel (plain launch, 124KB dynamic LDS) ----
    PArgs a;
    a.x = x;
    for (int l = 0; l < 3; ++l) {
        a.wih[l] = wihf[l];
        a.whh_src[l] = whh[l];
        a.bih[l] = bih[l];
        a.bhh[l] = bhh[l];
    }
    a.hseq = hseq; a.h32 = h32;
    a.out_h = (float*)d_out + (size_t)TT * BB * OO;
    a.flags = bararea;
    a.rel = bararea + 224;

    hipFuncSetAttribute((const void*)gru_persistent,
                        hipFuncAttributeMaxDynamicSharedMemorySize, LDS_TOTAL);
    gru_persistent<<<NBLK, 512, LDS_TOTAL, stream>>>(a);

    // ---- final FC ----
    fc_kernel<<<1024, 256, 0, stream>>>(hseq, fcw16, fc_b, (float*)d_out);
}